// Round 1
// baseline (1917.105 us; speedup 1.0000x reference)
//
#include <hip/hip_runtime.h>
#include <hip/hip_bf16.h>

#define BATCH 1024
#define SEQN  512
#define EMBD  50
#define HID   64
#define G4    256      // 4*HID
#define KTOT  114      // EMBD + HID
#define RPB   2        // rows per block (grid 512 => 2 blocks/CU)
#define NC    50000
#define CPT   4        // fc: cols per thread

__device__ __forceinline__ float rlane(float v, int l) {
    return __uint_as_float(__builtin_amdgcn_readlane(__float_as_uint(v), l));
}

// ---------------------------------------------------------------------------
// Kernel 1: fused embedding gather + 512-step LSTM. One block = 2 batch rows.
// W_ih|W_hh rows live in 114 VGPRs per thread (thread t owns gate-unit t).
// X (=[e_t ; h]) is lane-distributed per row; broadcast via v_readlane so the
// inner k-loop is pure VALU (no LDS reads).
// ---------------------------------------------------------------------------
__global__ __launch_bounds__(256, 2)
void lstm_fused(const int* __restrict__ x, const float* __restrict__ emb,
                const float* __restrict__ W_ih, const float* __restrict__ W_hh,
                const float* __restrict__ b_ih, const float* __restrict__ b_hh,
                float* __restrict__ hF)
{
    __shared__ float hbuf[RPB][HID];
    __shared__ float gbuf[RPB][G4];
    __shared__ int   xbuf[RPB][SEQN];

    const int t    = threadIdx.x;     // gate-unit index 0..255
    const int lane = t & 63;
    const int row0 = blockIdx.x * RPB;

    // persistent weights in registers: w[k] = W[unit t][k], k = [e(50) ; h(64)]
    float w[KTOT];
#pragma unroll
    for (int k = 0; k < EMBD; ++k) w[k] = W_ih[t * EMBD + k];
#pragma unroll
    for (int k = 0; k < HID; ++k)  w[EMBD + k] = W_hh[t * HID + k];
    const float bsum = b_ih[t] + b_hh[t];

    // stage this block's token indices
    for (int i = t; i < RPB * SEQN; i += 256)
        xbuf[i >> 9][i & (SEQN - 1)] = x[(row0 + (i >> 9)) * SEQN + (i & (SEQN - 1))];
    if (t < RPB * HID) hbuf[t >> 6][t & 63] = 0.0f;
    float c = 0.0f;   // owned by threads t<128: (row = t>>6, unit j = t&63)
    __syncthreads();

    // prefetch embeddings for step 0 (lane-distributed: lane<50 holds e[lane])
    float ecur[RPB];
#pragma unroll
    for (int r = 0; r < RPB; ++r)
        ecur[r] = (lane < EMBD) ? emb[xbuf[r][0] * EMBD + lane] : 0.0f;

    for (int s = 0; s < SEQN; ++s) {
        // assemble lane-distributed X: Xa holds X[0..63], Xb holds X[64..113]
        float Xa[RPB], Xb[RPB];
#pragma unroll
        for (int r = 0; r < RPB; ++r) {
            Xa[r] = (lane < EMBD) ? ecur[r] : hbuf[r][lane - EMBD];
            Xb[r] = (lane < EMBD) ? hbuf[r][lane + (HID - EMBD)] : 0.0f;
        }
        // prefetch next step's embeddings (covered by the k-loop below)
        if (s + 1 < SEQN) {
#pragma unroll
            for (int r = 0; r < RPB; ++r)
                ecur[r] = (lane < EMBD) ? emb[xbuf[r][s + 1] * EMBD + lane] : 0.0f;
        }

        float acc[RPB];
#pragma unroll
        for (int r = 0; r < RPB; ++r) acc[r] = bsum;
#pragma unroll
        for (int k = 0; k < KTOT; ++k) {
            const float wk = w[k];
#pragma unroll
            for (int r = 0; r < RPB; ++r) {
                const float xv = (k < 64) ? rlane(Xa[r], k) : rlane(Xb[r], k - 64);
                acc[r] = fmaf(xv, wk, acc[r]);
            }
        }

#pragma unroll
        for (int r = 0; r < RPB; ++r) gbuf[r][t] = acc[r];
        __syncthreads();
        if (t < RPB * HID) {
            const int rr = t >> 6, j = t & 63;
            const float gi = gbuf[rr][j];
            const float gf = gbuf[rr][HID + j];
            const float gg = gbuf[rr][2 * HID + j];
            const float go = gbuf[rr][3 * HID + j];
            const float i_ = 1.0f / (1.0f + __expf(-gi));
            const float f_ = 1.0f / (1.0f + __expf(-gf));
            const float e2 = __expf(2.0f * gg);
            const float g_ = 1.0f - 2.0f / (e2 + 1.0f);   // tanh, inf-safe
            const float o_ = 1.0f / (1.0f + __expf(-go));
            c = fmaf(f_, c, i_ * g_);
            const float e2c = __expf(2.0f * c);
            hbuf[rr][j] = o_ * (1.0f - 2.0f / (e2c + 1.0f));
        }
        __syncthreads();
    }
    if (t < RPB * HID)
        hF[(row0 + (t >> 6)) * HID + (t & 63)] = hbuf[t >> 6][t & 63];
}

// ---------------------------------------------------------------------------
// FC + softmax (no max needed: |logit| < ~4, exp cannot overflow in fp32).
// ---------------------------------------------------------------------------
__global__ void zero_s(float* S) {
    const int i = blockIdx.x * 256 + threadIdx.x;
    if (i < BATCH) S[i] = 0.0f;
}

// grid (ceil(NC/1024), 16). Thread owns 4 cols; W_fc row in 64 VGPRs;
// h row is wave-uniform -> scalar loads + SGPR-operand FMAs.
__global__ __launch_bounds__(256, 4)
void fc_sumexp(const float* __restrict__ hF, const float* __restrict__ W_fc,
               const float* __restrict__ b_fc, float* __restrict__ S)
{
    const int t    = threadIdx.x;
    const int lane = t & 63;
    const int row0 = blockIdx.y * 64;
    for (int cc = 0; cc < CPT; ++cc) {
        const int n = blockIdx.x * (256 * CPT) + cc * 256 + t;
        const bool valid = (n < NC);
        float wv[HID];
        if (valid) {
            const float4* wp = (const float4*)(W_fc + (size_t)n * HID);
#pragma unroll
            for (int q = 0; q < HID / 4; ++q) {
                const float4 v = wp[q];
                wv[4 * q] = v.x; wv[4 * q + 1] = v.y; wv[4 * q + 2] = v.z; wv[4 * q + 3] = v.w;
            }
        } else {
#pragma unroll
            for (int q = 0; q < HID; ++q) wv[q] = 0.0f;
        }
        const float bf = valid ? b_fc[n] : 0.0f;
        for (int r = 0; r < 64; ++r) {
            const float4* hp = (const float4*)(hF + (size_t)(row0 + r) * HID);
            float l = bf;
#pragma unroll
            for (int q = 0; q < HID / 4; ++q) {
                const float4 hq = hp[q];
                l = fmaf(hq.x, wv[4 * q], l);
                l = fmaf(hq.y, wv[4 * q + 1], l);
                l = fmaf(hq.z, wv[4 * q + 2], l);
                l = fmaf(hq.w, wv[4 * q + 3], l);
            }
            float ex = valid ? __expf(l) : 0.0f;
            ex += __shfl_down(ex, 32);
            ex += __shfl_down(ex, 16);
            ex += __shfl_down(ex, 8);
            ex += __shfl_down(ex, 4);
            ex += __shfl_down(ex, 2);
            ex += __shfl_down(ex, 1);
            if (lane == 0) atomicAdd(&S[row0 + r], ex);
        }
    }
}

__global__ __launch_bounds__(256, 4)
void fc_probs(const float* __restrict__ hF, const float* __restrict__ W_fc,
              const float* __restrict__ b_fc, const float* __restrict__ S,
              float* __restrict__ out)
{
    __shared__ float sinv[64];
    const int t    = threadIdx.x;
    const int row0 = blockIdx.y * 64;
    if (t < 64) sinv[t] = 1.0f / S[row0 + t];
    __syncthreads();
    for (int cc = 0; cc < CPT; ++cc) {
        const int n = blockIdx.x * (256 * CPT) + cc * 256 + t;
        if (n >= NC) continue;   // monotonic in cc; no barriers below
        float wv[HID];
        const float4* wp = (const float4*)(W_fc + (size_t)n * HID);
#pragma unroll
        for (int q = 0; q < HID / 4; ++q) {
            const float4 v = wp[q];
            wv[4 * q] = v.x; wv[4 * q + 1] = v.y; wv[4 * q + 2] = v.z; wv[4 * q + 3] = v.w;
        }
        const float bf = b_fc[n];
        for (int r = 0; r < 64; ++r) {
            const float4* hp = (const float4*)(hF + (size_t)(row0 + r) * HID);
            float l = bf;
#pragma unroll
            for (int q = 0; q < HID / 4; ++q) {
                const float4 hq = hp[q];
                l = fmaf(hq.x, wv[4 * q], l);
                l = fmaf(hq.y, wv[4 * q + 1], l);
                l = fmaf(hq.z, wv[4 * q + 2], l);
                l = fmaf(hq.w, wv[4 * q + 3], l);
            }
            out[(size_t)(row0 + r) * NC + n] = __expf(l) * sinv[r];
        }
    }
}

extern "C" void kernel_launch(void* const* d_in, const int* in_sizes, int n_in,
                              void* d_out, int out_size, void* d_ws, size_t ws_size,
                              hipStream_t stream) {
    (void)in_sizes; (void)n_in; (void)out_size; (void)ws_size;
    const int*   x    = (const int*)  d_in[0];
    const float* emb  = (const float*)d_in[1];
    const float* W_ih = (const float*)d_in[2];
    const float* W_hh = (const float*)d_in[3];
    const float* b_ih = (const float*)d_in[4];
    const float* b_hh = (const float*)d_in[5];
    const float* W_fc = (const float*)d_in[6];
    const float* b_fc = (const float*)d_in[7];
    float* out = (float*)d_out;

    float* hF = (float*)d_ws;                          // 1024*64 fp32 = 256 KB
    float* S  = (float*)((char*)d_ws + BATCH * HID * 4); // 1024 fp32

    hipLaunchKernelGGL(zero_s, dim3(4), dim3(256), 0, stream, S);
    hipLaunchKernelGGL(lstm_fused, dim3(BATCH / RPB), dim3(256), 0, stream,
                       x, emb, W_ih, W_hh, b_ih, b_hh, hF);
    const int gx = (NC + 256 * CPT - 1) / (256 * CPT); // 49
    dim3 g2(gx, 16);
    hipLaunchKernelGGL(fc_sumexp, g2, dim3(256), 0, stream, hF, W_fc, b_fc, S);
    hipLaunchKernelGGL(fc_probs,  g2, dim3(256), 0, stream, hF, W_fc, b_fc, S, out);
}

// Round 2
// 1561.395 us; speedup vs baseline: 1.2278x; 1.2278x over previous
//
#include <hip/hip_runtime.h>
#include <hip/hip_bf16.h>

#define BATCH 1024
#define SEQN  512
#define EMBD  50
#define HID   64
#define G4    256      // 4*HID
#define KTOT  114      // EMBD + HID
#define RPB   2        // rows per block (grid 512 => 2 blocks/CU)
#define NC    50000
#define NC4   (NC / 4) // 12500 float4 per row

__device__ __forceinline__ float rlane(float v, int l) {
    return __uint_as_float(__builtin_amdgcn_readlane(__float_as_uint(v), l));
}

// ---------------------------------------------------------------------------
// Kernel 1: fused embedding gather + 512-step LSTM. One block = 2 batch rows.
// Thread t owns gate-unit t; its W_ih|W_hh row (114 floats) is PINNED in
// VGPRs via empty inline asm (round-1 counters showed VGPR=72: the compiler
// had sunk the weight loads into the step loop -> ~30 GB of L2 reloads).
// X = [e_t ; h] is lane-distributed; broadcast via v_readlane (VALU pipe).
// ---------------------------------------------------------------------------
__global__ __launch_bounds__(256, 2)
void lstm_fused(const int* __restrict__ x, const float* __restrict__ emb,
                const float* __restrict__ W_ih, const float* __restrict__ W_hh,
                const float* __restrict__ b_ih, const float* __restrict__ b_hh,
                float* __restrict__ hF)
{
    __shared__ float hbuf[RPB][HID];
    __shared__ float gbuf[RPB][G4];
    __shared__ int   xbuf[RPB][SEQN];

    const int t    = threadIdx.x;     // gate-unit index 0..255
    const int lane = t & 63;
    const int row0 = blockIdx.x * RPB;

    // persistent weights in registers: w[k] = W[unit t][k], k = [e(50) ; h(64)]
    float w[KTOT];
#pragma unroll
    for (int k = 0; k < EMBD; ++k) w[k] = W_ih[t * EMBD + k];
#pragma unroll
    for (int k = 0; k < HID; ++k)  w[EMBD + k] = W_hh[t * HID + k];
    float bsum = b_ih[t] + b_hh[t];
    // Pin: force register residency, forbid rematerialization inside the loop.
#pragma unroll
    for (int k = 0; k < KTOT; ++k) asm volatile("" : "+v"(w[k]));
    asm volatile("" : "+v"(bsum));

    // stage this block's token indices
    for (int i = t; i < RPB * SEQN; i += 256)
        xbuf[i >> 9][i & (SEQN - 1)] = x[(row0 + (i >> 9)) * SEQN + (i & (SEQN - 1))];
    if (t < RPB * HID) hbuf[t >> 6][t & 63] = 0.0f;
    float c = 0.0f;   // owned by threads t<128: (row = t>>6, unit j = t&63)
    __syncthreads();

    // prefetch embeddings for step 0 (lane-distributed: lane<50 holds e[lane])
    float ecur[RPB];
#pragma unroll
    for (int r = 0; r < RPB; ++r)
        ecur[r] = (lane < EMBD) ? emb[xbuf[r][0] * EMBD + lane] : 0.0f;

    for (int s = 0; s < SEQN; ++s) {
        // assemble lane-distributed X: Xa holds X[0..63], Xb holds X[64..113]
        float Xa[RPB], Xb[RPB];
#pragma unroll
        for (int r = 0; r < RPB; ++r) {
            Xa[r] = (lane < EMBD) ? ecur[r] : hbuf[r][lane - EMBD];
            Xb[r] = (lane < EMBD) ? hbuf[r][lane + (HID - EMBD)] : 0.0f;
        }
        // prefetch next step's embeddings (covered by the k-loop below)
        if (s + 1 < SEQN) {
#pragma unroll
            for (int r = 0; r < RPB; ++r)
                ecur[r] = (lane < EMBD) ? emb[xbuf[r][s + 1] * EMBD + lane] : 0.0f;
        }

        float acc[RPB];
#pragma unroll
        for (int r = 0; r < RPB; ++r) acc[r] = bsum;
#pragma unroll
        for (int k = 0; k < KTOT; ++k) {
            const float wk = w[k];
#pragma unroll
            for (int r = 0; r < RPB; ++r) {
                const float xv = (k < 64) ? rlane(Xa[r], k) : rlane(Xb[r], k - 64);
                acc[r] = fmaf(xv, wk, acc[r]);
            }
        }

#pragma unroll
        for (int r = 0; r < RPB; ++r) gbuf[r][t] = acc[r];
        __syncthreads();
        if (t < RPB * HID) {
            const int rr = t >> 6, j = t & 63;
            const float gi = gbuf[rr][j];
            const float gf = gbuf[rr][HID + j];
            const float gg = gbuf[rr][2 * HID + j];
            const float go = gbuf[rr][3 * HID + j];
            const float i_ = 1.0f / (1.0f + __expf(-gi));
            const float f_ = 1.0f / (1.0f + __expf(-gf));
            const float e2 = __expf(2.0f * gg);
            const float g_ = 1.0f - 2.0f / (e2 + 1.0f);   // tanh, inf-safe
            const float o_ = 1.0f / (1.0f + __expf(-go));
            c = fmaf(f_, c, i_ * g_);
            const float e2c = __expf(2.0f * c);
            hbuf[rr][j] = o_ * (1.0f - 2.0f / (e2c + 1.0f));
        }
        __syncthreads();
    }
    if (t < RPB * HID)
        hF[(row0 + (t >> 6)) * HID + (t & 63)] = hbuf[t >> 6][t & 63];
}

// ---------------------------------------------------------------------------
// FC + softmax, computed ONCE (no recompute pass):
//   fc_exp:     out[b][n] = exp(logit)          (compute-bound, 8-row ILP)
//   row_sum:    S[b] = sum_n out[b][n]          (BW-bound)
//   scale_rows: out[b][n] *= 1/S[b]             (BW-bound)
// No max-subtraction needed: |logit| < ~4, fp32 exp cannot overflow.
// ---------------------------------------------------------------------------
__global__ void zero_s(float* S) {
    const int i = blockIdx.x * 256 + threadIdx.x;
    if (i < BATCH) S[i] = 0.0f;
}

// grid (196, 16): x covers 196*256 >= 50000 cols, y covers 16*64 batch rows.
__global__ __launch_bounds__(256, 3)
void fc_exp(const float* __restrict__ hF, const float* __restrict__ W_fc,
            const float* __restrict__ b_fc, float* __restrict__ out)
{
    const int t    = threadIdx.x;
    const int row0 = blockIdx.y * 64;
    const int n    = blockIdx.x * 256 + t;
    const bool valid = (n < NC);

    float wv[HID];
    if (valid) {
        const float4* wp = (const float4*)(W_fc + (size_t)n * HID);
#pragma unroll
        for (int q = 0; q < HID / 4; ++q) {
            const float4 v = wp[q];
            wv[4 * q] = v.x; wv[4 * q + 1] = v.y; wv[4 * q + 2] = v.z; wv[4 * q + 3] = v.w;
        }
    } else {
#pragma unroll
        for (int q = 0; q < HID; ++q) wv[q] = 0.0f;
    }
    const float bf = valid ? b_fc[n] : 0.0f;

    const float4* hbase = (const float4*)hF;   // [row][16] float4 chunks
    for (int r0 = 0; r0 < 64; r0 += 8) {       // 8 independent acc chains
        float l8[8];
#pragma unroll
        for (int j = 0; j < 8; ++j) l8[j] = bf;
#pragma unroll
        for (int q = 0; q < HID / 4; ++q) {
#pragma unroll
            for (int j = 0; j < 8; ++j) {
                const float4 hq = hbase[(size_t)(row0 + r0 + j) * 16 + q];
                l8[j] = fmaf(hq.x, wv[4 * q],     l8[j]);
                l8[j] = fmaf(hq.y, wv[4 * q + 1], l8[j]);
                l8[j] = fmaf(hq.z, wv[4 * q + 2], l8[j]);
                l8[j] = fmaf(hq.w, wv[4 * q + 3], l8[j]);
            }
        }
        if (valid) {
#pragma unroll
            for (int j = 0; j < 8; ++j)
                out[(size_t)(row0 + r0 + j) * NC + n] = __expf(l8[j]);
        }
    }
}

// grid (49, 1024): each block reduces a 1024-col strip of one row.
__global__ __launch_bounds__(256, 4)
void row_sum(const float* __restrict__ out, float* __restrict__ S)
{
    __shared__ float part[4];
    const int t    = threadIdx.x;
    const int lane = t & 63;
    const int row  = blockIdx.y;
    const int i    = blockIdx.x * 256 + t;
    float v = 0.0f;
    if (i < NC4) {
        const float4 u = ((const float4*)(out + (size_t)row * NC))[i];
        v = (u.x + u.y) + (u.z + u.w);
    }
    v += __shfl_down(v, 32);
    v += __shfl_down(v, 16);
    v += __shfl_down(v, 8);
    v += __shfl_down(v, 4);
    v += __shfl_down(v, 2);
    v += __shfl_down(v, 1);
    if (lane == 0) part[t >> 6] = v;
    __syncthreads();
    if (t == 0) atomicAdd(&S[row], (part[0] + part[1]) + (part[2] + part[3]));
}

// grid (49, 1024): out[row][:] *= 1/S[row]
__global__ __launch_bounds__(256, 4)
void scale_rows(float* __restrict__ out, const float* __restrict__ S)
{
    const int row = blockIdx.y;
    const int i   = blockIdx.x * 256 + threadIdx.x;
    if (i < NC4) {
        const float inv = 1.0f / S[row];
        float4* p = (float4*)(out + (size_t)row * NC) + i;
        float4 v = *p;
        v.x *= inv; v.y *= inv; v.z *= inv; v.w *= inv;
        *p = v;
    }
}

extern "C" void kernel_launch(void* const* d_in, const int* in_sizes, int n_in,
                              void* d_out, int out_size, void* d_ws, size_t ws_size,
                              hipStream_t stream) {
    (void)in_sizes; (void)n_in; (void)out_size; (void)ws_size;
    const int*   x    = (const int*)  d_in[0];
    const float* emb  = (const float*)d_in[1];
    const float* W_ih = (const float*)d_in[2];
    const float* W_hh = (const float*)d_in[3];
    const float* b_ih = (const float*)d_in[4];
    const float* b_hh = (const float*)d_in[5];
    const float* W_fc = (const float*)d_in[6];
    const float* b_fc = (const float*)d_in[7];
    float* out = (float*)d_out;

    float* hF = (float*)d_ws;                            // 1024*64 fp32 = 256 KB
    float* S  = (float*)((char*)d_ws + BATCH * HID * 4); // 1024 fp32

    hipLaunchKernelGGL(zero_s, dim3(4), dim3(256), 0, stream, S);
    hipLaunchKernelGGL(lstm_fused, dim3(BATCH / RPB), dim3(256), 0, stream,
                       x, emb, W_ih, W_hh, b_ih, b_hh, hF);
    hipLaunchKernelGGL(fc_exp, dim3(196, 16), dim3(256), 0, stream,
                       hF, W_fc, b_fc, out);
    hipLaunchKernelGGL(row_sum, dim3(49, BATCH), dim3(256), 0, stream, out, S);
    hipLaunchKernelGGL(scale_rows, dim3(49, BATCH), dim3(256), 0, stream, out, S);
}

// Round 3
// 953.284 us; speedup vs baseline: 2.0111x; 1.6379x over previous
//
#include <hip/hip_runtime.h>
#include <hip/hip_bf16.h>

#define BATCH 1024
#define SEQN  512
#define EMBD  50
#define HID   64
#define NC    50000
#define KPAD  128            // padded K = EMBD(50) + HID(64) -> 128
#define XSTR  136            // XH row stride in fp16 (pad: 2-way banks, 16B-aligned)
#define RPBK  16             // batch rows per LSTM block (one M-tile)

typedef _Float16 half8 __attribute__((ext_vector_type(8)));
typedef float    f32x4 __attribute__((ext_vector_type(4)));

// W row for gate g, k-index over X=[e(0..50)|h(50..114)|0]
__device__ __forceinline__ float wrow(const float* __restrict__ W_ih,
                                      const float* __restrict__ W_hh,
                                      int g, int k) {
    if (k < EMBD)        return W_ih[g * EMBD + k];
    if (k < EMBD + HID)  return W_hh[g * HID + (k - EMBD)];
    return 0.0f;
}

// ---------------------------------------------------------------------------
// LSTM: 64 blocks x 256 thr. Block owns 16 rows (M-tile). W held as persistent
// B-fragments in VGPRs (loaded once). B columns PERMUTED: col (64w+16nt+c)
// holds gate 64*nt + 16w + c  => lane's acc[nt] = gate-type nt of unit 16w+c
// for rows 4q+reg  => gate epilogue entirely in registers. 2 barriers/step.
// ---------------------------------------------------------------------------
__global__ __launch_bounds__(256, 1)
void lstm_mfma(const int* __restrict__ x, const float* __restrict__ emb,
               const float* __restrict__ W_ih, const float* __restrict__ W_hh,
               const float* __restrict__ b_ih, const float* __restrict__ b_hh,
               float* __restrict__ hF)
{
    __shared__ __align__(16) _Float16 XH[RPBK * XSTR];
    __shared__ int xbuf[RPBK * SEQN];

    const int t    = threadIdx.x;
    const int w    = t >> 6;        // wave 0..3
    const int lane = t & 63;
    const int q    = lane >> 4;     // quad 0..3
    const int cc   = lane & 15;
    const int r0   = blockIdx.x * RPBK;
    const int u    = 16 * w + cc;   // unit 0..63 owned by this lane

    // --- persistent B-fragments (W^T, gate-permuted), loaded once ---
    half8 Bf[4][4];                 // [kt][nt]
#pragma unroll
    for (int kt = 0; kt < 4; ++kt)
#pragma unroll
        for (int nt = 0; nt < 4; ++nt) {
            const int g = 64 * nt + u;          // actual gate row
#pragma unroll
            for (int j = 0; j < 8; ++j) {
                const int k = 32 * kt + 8 * q + j;
                Bf[kt][nt][j] = (_Float16)wrow(W_ih, W_hh, g, k);
            }
        }
    float bias[4];
#pragma unroll
    for (int nt = 0; nt < 4; ++nt) {
        const int g = 64 * nt + u;
        bias[nt] = b_ih[g] + b_hh[g];
    }

    // --- stage token indices (coalesced) ---
    for (int i = t; i < RPBK * SEQN; i += 256)
        xbuf[i] = x[(size_t)(r0 + (i >> 9)) * SEQN + (i & (SEQN - 1))];

    // --- init XH: zeros (h=0, pad=0), then e for s=0 ---
    for (int i = t; i < RPBK * XSTR; i += 256) XH[i] = (_Float16)0.0f;
    __syncthreads();
    if (lane < EMBD) {
#pragma unroll
        for (int ii = 0; ii < 4; ++ii) {
            const int m = (t >> 6) + 4 * ii;
            XH[m * XSTR + lane] = (_Float16)emb[(size_t)xbuf[m * SEQN] * EMBD + lane];
        }
    }
    __syncthreads();

    float cst[4] = {0.0f, 0.0f, 0.0f, 0.0f};   // c for rows 4q+reg, unit u
    float hreg[4];

    for (int s = 0; s < SEQN; ++s) {
        // A-fragments from XH (XH valid here)
        half8 Af[4];
#pragma unroll
        for (int kt = 0; kt < 4; ++kt)
            Af[kt] = *(const half8*)&XH[cc * XSTR + 32 * kt + 8 * q];

        // prefetch next step's embeddings (latency hidden by MFMA+epilogue)
        float ev[4];
        const int sn = (s + 1 < SEQN) ? s + 1 : s;
        if (lane < EMBD) {
#pragma unroll
            for (int ii = 0; ii < 4; ++ii) {
                const int m = (t >> 6) + 4 * ii;
                ev[ii] = emb[(size_t)xbuf[m * SEQN + sn] * EMBD + lane];
            }
        }

        f32x4 acc[4];
#pragma unroll
        for (int nt = 0; nt < 4; ++nt) acc[nt] = (f32x4){0.f, 0.f, 0.f, 0.f};
#pragma unroll
        for (int nt = 0; nt < 4; ++nt)
#pragma unroll
            for (int kt = 0; kt < 4; ++kt)
                acc[nt] = __builtin_amdgcn_mfma_f32_16x16x32_f16(Af[kt], Bf[kt][nt], acc[nt], 0, 0, 0);

        // register-only gate epilogue: acc[0..3][reg] = i,f,g,o preacts
#pragma unroll
        for (int reg = 0; reg < 4; ++reg) {
            const float gi = acc[0][reg] + bias[0];
            const float gf = acc[1][reg] + bias[1];
            const float gg = acc[2][reg] + bias[2];
            const float go = acc[3][reg] + bias[3];
            const float i_ = 1.0f / (1.0f + __expf(-gi));
            const float f_ = 1.0f / (1.0f + __expf(-gf));
            const float e2 = __expf(2.0f * gg);
            const float g_ = 1.0f - 2.0f / (e2 + 1.0f);
            const float o_ = 1.0f / (1.0f + __expf(-go));
            cst[reg] = fmaf(f_, cst[reg], i_ * g_);
            const float ec = __expf(2.0f * cst[reg]);
            hreg[reg] = o_ * (1.0f - 2.0f / (ec + 1.0f));
        }

        __syncthreads();   // all waves consumed XH (A-frags) for step s

        // write h (rows 4q+reg, unit u) and next e into XH
#pragma unroll
        for (int reg = 0; reg < 4; ++reg)
            XH[(4 * q + reg) * XSTR + EMBD + u] = (_Float16)hreg[reg];
        if (lane < EMBD) {
#pragma unroll
            for (int ii = 0; ii < 4; ++ii) {
                const int m = (t >> 6) + 4 * ii;
                XH[m * XSTR + lane] = (_Float16)ev[ii];
            }
        }
        if (s == SEQN - 1) {
#pragma unroll
            for (int reg = 0; reg < 4; ++reg)
                hF[(size_t)(r0 + 4 * q + reg) * HID + u] = hreg[reg];
        }
        __syncthreads();   // XH ready for step s+1
    }
}

// ---------------------------------------------------------------------------
// FC + softmax, two-pass MFMA recompute (no max: |logit| < ~4).
//   pass A (WRITE=false): row-sums of exp(logits) -> atomicAdd S
//   pass B (WRITE=true) : out = exp(logit) / S[row]
// Block: 64 rows x 256 cols; wave w owns col slice [64w,64w+64).
// ---------------------------------------------------------------------------
__global__ void zero_s(float* S) {
    const int i = blockIdx.x * 256 + threadIdx.x;
    if (i < BATCH) S[i] = 0.0f;
}

template <bool WRITE>
__global__ __launch_bounds__(256, 2)
void fc_pass(const float* __restrict__ hF, const float* __restrict__ W_fc,
             const float* __restrict__ b_fc, float* __restrict__ S,
             float* __restrict__ out)
{
    __shared__ float sinv[64];
    const int t    = threadIdx.x;
    const int w    = t >> 6;
    const int lane = t & 63;
    const int q    = lane >> 4;
    const int cc   = lane & 15;
    const int row0 = blockIdx.y * 64;
    const int n0   = blockIdx.x * 256;

    if (WRITE) {
        if (t < 64) sinv[t] = 1.0f / S[row0 + t];
        __syncthreads();
    }

    // A-frags: h rows (fp32 -> fp16), [mt][kt]
    half8 Af[4][2];
#pragma unroll
    for (int mt = 0; mt < 4; ++mt)
#pragma unroll
        for (int kt = 0; kt < 2; ++kt) {
            const float* p = hF + (size_t)(row0 + 16 * mt + cc) * HID + 32 * kt + 8 * q;
#pragma unroll
            for (int j = 0; j < 8; ++j) Af[mt][kt][j] = (_Float16)p[j];
        }

    // B-frags: W_fc rows (cols of logits), clamped at NC
    half8 Bf[4][2];
    float bias[4];
#pragma unroll
    for (int nt = 0; nt < 4; ++nt) {
        int n = n0 + 64 * w + 16 * nt + cc;
        const int nl = (n < NC) ? n : NC - 1;
        bias[nt] = b_fc[nl];
#pragma unroll
        for (int kt = 0; kt < 2; ++kt) {
            const float* p = W_fc + (size_t)nl * HID + 32 * kt + 8 * q;
#pragma unroll
            for (int j = 0; j < 8; ++j) Bf[nt][kt][j] = (_Float16)p[j];
        }
    }

    f32x4 acc[4][4];   // [mt][nt]
#pragma unroll
    for (int mt = 0; mt < 4; ++mt)
#pragma unroll
        for (int nt = 0; nt < 4; ++nt) acc[mt][nt] = (f32x4){0.f, 0.f, 0.f, 0.f};
#pragma unroll
    for (int mt = 0; mt < 4; ++mt)
#pragma unroll
        for (int nt = 0; nt < 4; ++nt)
#pragma unroll
            for (int kt = 0; kt < 2; ++kt)
                acc[mt][nt] = __builtin_amdgcn_mfma_f32_16x16x32_f16(Af[mt][kt], Bf[nt][kt], acc[mt][nt], 0, 0, 0);

    if (!WRITE) {
        float rs[4][4];   // [mt][reg] partial row-sums over this wave's 64 cols
#pragma unroll
        for (int mt = 0; mt < 4; ++mt)
#pragma unroll
            for (int reg = 0; reg < 4; ++reg) rs[mt][reg] = 0.0f;
#pragma unroll
        for (int mt = 0; mt < 4; ++mt)
#pragma unroll
            for (int nt = 0; nt < 4; ++nt) {
                const int n = n0 + 64 * w + 16 * nt + cc;
#pragma unroll
                for (int reg = 0; reg < 4; ++reg) {
                    const float l = acc[mt][nt][reg] + bias[nt];
                    rs[mt][reg] += (n < NC) ? __expf(l) : 0.0f;
                }
            }
#pragma unroll
        for (int mt = 0; mt < 4; ++mt)
#pragma unroll
            for (int reg = 0; reg < 4; ++reg) {
                float v = rs[mt][reg];
                v += __shfl_xor(v, 1);
                v += __shfl_xor(v, 2);
                v += __shfl_xor(v, 4);
                v += __shfl_xor(v, 8);
                rs[mt][reg] = v;
            }
        if (cc == 0) {
#pragma unroll
            for (int mt = 0; mt < 4; ++mt)
#pragma unroll
                for (int reg = 0; reg < 4; ++reg)
                    atomicAdd(&S[row0 + 16 * mt + 4 * q + reg], rs[mt][reg]);
        }
    } else {
#pragma unroll
        for (int mt = 0; mt < 4; ++mt) {
            float si[4];
#pragma unroll
            for (int reg = 0; reg < 4; ++reg) si[reg] = sinv[16 * mt + 4 * q + reg];
#pragma unroll
            for (int nt = 0; nt < 4; ++nt) {
                const int n = n0 + 64 * w + 16 * nt + cc;
                if (n < NC) {
#pragma unroll
                    for (int reg = 0; reg < 4; ++reg) {
                        const float l = acc[mt][nt][reg] + bias[nt];
                        out[(size_t)(row0 + 16 * mt + 4 * q + reg) * NC + n] = __expf(l) * si[reg];
                    }
                }
            }
        }
    }
}

extern "C" void kernel_launch(void* const* d_in, const int* in_sizes, int n_in,
                              void* d_out, int out_size, void* d_ws, size_t ws_size,
                              hipStream_t stream) {
    (void)in_sizes; (void)n_in; (void)out_size; (void)ws_size;
    const int*   x    = (const int*)  d_in[0];
    const float* emb  = (const float*)d_in[1];
    const float* W_ih = (const float*)d_in[2];
    const float* W_hh = (const float*)d_in[3];
    const float* b_ih = (const float*)d_in[4];
    const float* b_hh = (const float*)d_in[5];
    const float* W_fc = (const float*)d_in[6];
    const float* b_fc = (const float*)d_in[7];
    float* out = (float*)d_out;

    float* hF = (float*)d_ws;                            // 1024*64 fp32 = 256 KB
    float* S  = (float*)((char*)d_ws + BATCH * HID * 4); // 1024 fp32

    hipLaunchKernelGGL(zero_s, dim3(4), dim3(256), 0, stream, S);
    hipLaunchKernelGGL(lstm_mfma, dim3(BATCH / RPBK), dim3(256), 0, stream,
                       x, emb, W_ih, W_hh, b_ih, b_hh, hF);
    dim3 g2((NC + 255) / 256, BATCH / 64);   // (196, 16)
    hipLaunchKernelGGL(fc_pass<false>, g2, dim3(256), 0, stream, hF, W_fc, b_fc, S, out);
    hipLaunchKernelGGL(fc_pass<true>,  g2, dim3(256), 0, stream, hF, W_fc, b_fc, S, out);
}